// Round 4
// baseline (37.933 us; speedup 1.0000x reference)
//
#include <hip/hip_runtime.h>

#define BATCH  32
#define S_DIM  16384
#define F_DIM  8
#define K_DIM  9
#define N_DIM  (S_DIM - K_DIM)   // 16375
#define R_OUT  4                 // outputs per thread

typedef __attribute__((ext_vector_type(4))) float f32x4;

// Thread -> 4 consecutive output rows. Loads rows n..n+10 (22 x 16B) into
// registers once; register sliding window gives 5.5 loads/output vs 16.
// No LDS, no barrier: waves stream loads/compute/stores independently.
__global__ __launch_bounds__(256) void peak2peak_kernel(
    const float* __restrict__ x,
    const float* __restrict__ W,
    const float* __restrict__ bias,
    float* __restrict__ out)
{
    const int t = threadIdx.x;
    const int b = blockIdx.y;
    const int n = (blockIdx.x * 256 + t) * R_OUT;
    if (n >= N_DIM) return;

    const float* xrow = x + ((long)b * S_DIM + n) * F_DIM;

    // 11 rows x 2 x f32x4, fully in registers
    f32x4 r[R_OUT + 7][2];
#pragma unroll
    for (int i = 0; i < R_OUT + 7; ++i) {
        r[i][0] = *reinterpret_cast<const f32x4*>(xrow + i * F_DIM);
        r[i][1] = *reinterpret_cast<const f32x4*>(xrow + i * F_DIM + 4);
    }

    const float bb = bias[0];

    float res[R_OUT][F_DIM];
#pragma unroll
    for (int i = 0; i < R_OUT; ++i) {
        float basev[F_DIM], acc[F_DIM];
#pragma unroll
        for (int f = 0; f < F_DIM; ++f) {
            basev[f] = r[i][f >> 2][f & 3] * W[f * K_DIM];   // W[f,0] — scalar loads
            acc[f]   = 0.f;
        }
#pragma unroll
        for (int k = 0; k < K_DIM - 1; ++k) {
#pragma unroll
            for (int f = 0; f < F_DIM; ++f) {
                acc[f] += fabsf(basev[f] - r[i + k][f >> 2][f & 3] * W[f * K_DIM + k + 1]);
            }
        }
#pragma unroll
        for (int f = 0; f < F_DIM; ++f) res[i][f] = acc[f] + bb;
    }

    float* orow = out + ((long)b * N_DIM + n) * F_DIM;
#pragma unroll
    for (int i = 0; i < R_OUT; ++i) {
        if (n + i < N_DIM) {
            f32x4 o0 = { res[i][0], res[i][1], res[i][2], res[i][3] };
            f32x4 o1 = { res[i][4], res[i][5], res[i][6], res[i][7] };
            __builtin_nontemporal_store(o0, reinterpret_cast<f32x4*>(orow + i * F_DIM));
            __builtin_nontemporal_store(o1, reinterpret_cast<f32x4*>(orow + i * F_DIM + 4));
        }
    }
}

extern "C" void kernel_launch(void* const* d_in, const int* in_sizes, int n_in,
                              void* d_out, int out_size, void* d_ws, size_t ws_size,
                              hipStream_t stream) {
    const float* x    = (const float*)d_in[0];
    const float* W    = (const float*)d_in[1];
    const float* bias = (const float*)d_in[2];
    float* out        = (float*)d_out;

    const int groups_per_batch = (N_DIM + R_OUT - 1) / R_OUT;        // 4094
    const int blocks_per_batch = (groups_per_batch + 255) / 256;     // 16
    dim3 grid(blocks_per_batch, BATCH);                              // 512 blocks

    peak2peak_kernel<<<grid, 256, 0, stream>>>(x, W, bias, out);
}

// Round 5
// 15.342 us; speedup vs baseline: 2.4725x; 2.4725x over previous
//
#include <hip/hip_runtime.h>

#define BATCH  32
#define S_DIM  16384
#define F_DIM  8
#define K_DIM  9
#define N_DIM  (S_DIM - K_DIM)   // 16375
#define NPB    1024              // outputs per block
#define R_OUT  4                 // outputs per thread
#define CHUNKS 2064              // 16B chunks staged: 2*(NPB+8) rows x 2 halves

typedef __attribute__((ext_vector_type(4))) float f32x4;

// Block = 256 threads -> 1024 consecutive output rows of one batch.
// Stage rows n0..n0+1031 (33 KB) into LDS with coalesced 16B loads,
// XOR-swizzled: chunk c = 2*row + half stored at c ^ ((c>>3)&7).
// Read pattern (4 outputs/thread): lane chunk-stride 8 -> unswizzled all
// lanes hit one bank column; swizzle cycles (c>>3)&7 per lane -> 8 lanes
// per 4-bank column = conflict-free minimum for wave64 b128.
__global__ __launch_bounds__(256) void peak2peak_kernel(
    const float* __restrict__ x,
    const float* __restrict__ W,
    const float* __restrict__ bias,
    float* __restrict__ out)
{
    __shared__ f32x4 lds4[CHUNKS];   // 33 KB

    const int t  = threadIdx.x;
    const int b  = blockIdx.y;
    const int n0 = blockIdx.x * NPB;

    const float* xbase = x + ((long)b * S_DIM + n0) * F_DIM;
    const int climit = 2 * (S_DIM - n0);   // chunks whose row is in-bounds

#pragma unroll
    for (int i = 0; i < 9; ++i) {
        int c = t + i * 256;
        if (c < CHUNKS && c < climit) {
            f32x4 v = *reinterpret_cast<const f32x4*>(xbase + c * 4);
            *reinterpret_cast<f32x4*>(
                reinterpret_cast<char*>(lds4) + ((c ^ ((c >> 3) & 7)) << 4)) = v;
        }
    }
    __syncthreads();

    const float bb = bias[0];
    float res[R_OUT][F_DIM];

#pragma unroll
    for (int j = 0; j < 2; ++j) {          // feature half: f = 4j .. 4j+3
        f32x4 rv[R_OUT + 8];               // rows 4t .. 4t+11, half j
#pragma unroll
        for (int k = 0; k < R_OUT + 8; ++k) {
            int c = 8 * t + 2 * k + j;
            int byteoff = (c ^ ((c >> 3) & 7)) << 4;
            rv[k] = *reinterpret_cast<const f32x4*>(
                reinterpret_cast<const char*>(lds4) + byteoff);
        }
#pragma unroll
        for (int i = 0; i < R_OUT; ++i) {
            float basev[4], acc[4];
#pragma unroll
            for (int f = 0; f < 4; ++f) {
                basev[f] = rv[i][f] * W[(4 * j + f) * K_DIM];   // W[f,0] scalar
                acc[f]   = 0.f;
            }
#pragma unroll
            for (int k = 0; k < 8; ++k) {
#pragma unroll
                for (int f = 0; f < 4; ++f) {
                    float d = __builtin_fmaf(-W[(4 * j + f) * K_DIM + k + 1],
                                             rv[i + k][f], basev[f]);
                    acc[f] += fabsf(d);   // v_add_f32 with abs() src modifier
                }
            }
#pragma unroll
            for (int f = 0; f < 4; ++f) res[i][4 * j + f] = acc[f] + bb;
        }
    }

    const int nb = n0 + R_OUT * t;
#pragma unroll
    for (int i = 0; i < R_OUT; ++i) {
        int n = nb + i;
        if (n < N_DIM) {
            float* orow = out + ((long)b * N_DIM + n) * F_DIM;
            f32x4 o0 = { res[i][0], res[i][1], res[i][2], res[i][3] };
            f32x4 o1 = { res[i][4], res[i][5], res[i][6], res[i][7] };
            *reinterpret_cast<f32x4*>(orow)     = o0;
            *reinterpret_cast<f32x4*>(orow + 4) = o1;
        }
    }
}

extern "C" void kernel_launch(void* const* d_in, const int* in_sizes, int n_in,
                              void* d_out, int out_size, void* d_ws, size_t ws_size,
                              hipStream_t stream) {
    const float* x    = (const float*)d_in[0];
    const float* W    = (const float*)d_in[1];
    const float* bias = (const float*)d_in[2];
    float* out        = (float*)d_out;

    const int blocks_per_batch = (N_DIM + NPB - 1) / NPB;   // 16
    dim3 grid(blocks_per_batch, BATCH);                     // 512 blocks

    peak2peak_kernel<<<grid, 256, 0, stream>>>(x, W, bias, out);
}

// Round 6
// 14.818 us; speedup vs baseline: 2.5599x; 1.0353x over previous
//
#include <hip/hip_runtime.h>

#define BATCH  32
#define S_DIM  16384
#define F_DIM  8
#define K_DIM  9
#define N_DIM  (S_DIM - K_DIM)   // 16375
#define NPB    512               // outputs per block
#define R_OUT  2                 // outputs per thread
#define CHUNKS 1040              // 16B chunks staged: (NPB+8) rows x 2 halves

typedef __attribute__((ext_vector_type(4))) float f32x4;

// Block = 256 threads -> 512 consecutive output rows of one batch.
// Stage rows n0..n0+519 (16.6 KB) into LDS, coalesced 16B loads,
// XOR-swizzled: chunk c = 2*row + half stored at byte (c ^ ((c>>3)&7)) << 4.
// Read c = 4t + 2k + j (lane chunk-stride 4): for any const d=2k+j,
// col(8m+r) = r ^ (m&7) -> exactly 8 lanes per 4-bank column = conflict-free.
// 1024 blocks = 4 blocks/CU (16 waves), 10 ds_read_b128 per output vs 16 (R2).
__global__ __launch_bounds__(256) void peak2peak_kernel(
    const float* __restrict__ x,
    const float* __restrict__ W,
    const float* __restrict__ bias,
    float* __restrict__ out)
{
    __shared__ f32x4 lds4[CHUNKS];   // 16640 B

    const int t  = threadIdx.x;
    const int b  = blockIdx.y;
    const int n0 = blockIdx.x * NPB;

    const float* xbase = x + ((long)b * S_DIM + n0) * F_DIM;
    const int climit = 2 * (S_DIM - n0);   // chunks whose row is in-bounds

#pragma unroll
    for (int i = 0; i < 5; ++i) {
        int c = t + i * 256;
        if (c < CHUNKS && c < climit) {
            f32x4 v = *reinterpret_cast<const f32x4*>(xbase + c * 4);
            *reinterpret_cast<f32x4*>(
                reinterpret_cast<char*>(lds4) + ((c ^ ((c >> 3) & 7)) << 4)) = v;
        }
    }
    __syncthreads();

    const float bb = bias[0];
    float res[R_OUT][F_DIM];

#pragma unroll
    for (int j = 0; j < 2; ++j) {          // feature half: f = 4j .. 4j+3
        f32x4 rv[R_OUT + 8];               // rows 2t .. 2t+9, half j
#pragma unroll
        for (int k = 0; k < R_OUT + 8; ++k) {
            int c = 4 * t + 2 * k + j;
            int byteoff = (c ^ ((c >> 3) & 7)) << 4;
            rv[k] = *reinterpret_cast<const f32x4*>(
                reinterpret_cast<const char*>(lds4) + byteoff);
        }
#pragma unroll
        for (int i = 0; i < R_OUT; ++i) {
            float basev[4], acc[4];
#pragma unroll
            for (int f = 0; f < 4; ++f) {
                basev[f] = rv[i][f] * W[(4 * j + f) * K_DIM];   // W[f,0] scalar
                acc[f]   = 0.f;
            }
#pragma unroll
            for (int k = 0; k < 8; ++k) {
#pragma unroll
                for (int f = 0; f < 4; ++f) {
                    float d = __builtin_fmaf(-W[(4 * j + f) * K_DIM + k + 1],
                                             rv[i + k][f], basev[f]);
                    acc[f] += fabsf(d);   // v_add_f32 with abs() src modifier
                }
            }
#pragma unroll
            for (int f = 0; f < 4; ++f) res[i][4 * j + f] = acc[f] + bb;
        }
    }

    const int nb = n0 + R_OUT * t;
#pragma unroll
    for (int i = 0; i < R_OUT; ++i) {
        int n = nb + i;
        if (n < N_DIM) {
            float* orow = out + ((long)b * N_DIM + n) * F_DIM;
            f32x4 o0 = { res[i][0], res[i][1], res[i][2], res[i][3] };
            f32x4 o1 = { res[i][4], res[i][5], res[i][6], res[i][7] };
            *reinterpret_cast<f32x4*>(orow)     = o0;
            *reinterpret_cast<f32x4*>(orow + 4) = o1;
        }
    }
}

extern "C" void kernel_launch(void* const* d_in, const int* in_sizes, int n_in,
                              void* d_out, int out_size, void* d_ws, size_t ws_size,
                              hipStream_t stream) {
    const float* x    = (const float*)d_in[0];
    const float* W    = (const float*)d_in[1];
    const float* bias = (const float*)d_in[2];
    float* out        = (float*)d_out;

    const int blocks_per_batch = (N_DIM + NPB - 1) / NPB;   // 32
    dim3 grid(blocks_per_batch, BATCH);                     // 1024 blocks

    peak2peak_kernel<<<grid, 256, 0, stream>>>(x, W, bias, out);
}

// Round 7
// 12.551 us; speedup vs baseline: 3.0222x; 1.1806x over previous
//
#include <hip/hip_runtime.h>

#define BATCH  32
#define S_DIM  16384
#define F_DIM  8
#define K_DIM  9
#define N_DIM  (S_DIM - K_DIM)   // 16375
#define RCH    144               // 16B chunks per wave region: (64+8) rows x 2

typedef __attribute__((ext_vector_type(4))) float f32x4;

// Wave-private, barrier-free staging. Each wave owns 64 output rows:
// stages rows n0..n0+71 (144 chunks, 2.3 KB) into its own LDS region with
// coalesced 16B loads, then reads back wave-synchronously (same wave wrote
// it; lgkmcnt ordering suffices — NO __syncthreads in the kernel). Waves
// drift freely so stage/compute/store phases overlap across the 32
// resident waves per CU instead of convoying through barriers.
// Swizzle: chunk c stored at byte (c ^ ((c>>3)&7)) << 4 (bijective per
// 8-chunk group). Read c = 2*(lane+k)+j: low bits {j,2+j,4+j,6+j} xor'd
// with (c>>3)&7 spread 64 lanes 8-per-16B-column = 2 lanes/bank = free.
__global__ __launch_bounds__(256, 8) void peak2peak_kernel(
    const float* __restrict__ x,
    const float* __restrict__ W,
    const float* __restrict__ bias,
    float* __restrict__ out)
{
    __shared__ f32x4 lds4[4 * RCH];   // 9216 B

    const int t    = threadIdx.x;
    const int w    = t >> 6;          // wave id within block
    const int lane = t & 63;
    const int b    = blockIdx.y;
    const int n0   = blockIdx.x * 256 + w * 64;   // wave's first output row

    char* wbase = reinterpret_cast<char*>(lds4 + w * RCH);
    const float* xbase = x + ((long)b * S_DIM + n0) * F_DIM;

    int climit = 2 * (S_DIM - n0);    // chunks whose source row exists
    if (climit > RCH) climit = RCH;

#pragma unroll
    for (int i = 0; i < 3; ++i) {     // 144 chunks: 2 full insts + 16 lanes
        int c = lane + i * 64;
        if (c < climit) {
            f32x4 v = *reinterpret_cast<const f32x4*>(xbase + c * 4);
            *reinterpret_cast<f32x4*>(wbase + ((c ^ ((c >> 3) & 7)) << 4)) = v;
        }
    }
    // wave-synchronous LDS: compiler's lgkmcnt wait orders write->read.

    const float bb = bias[0];
    const int n = n0 + lane;
    const bool valid = (n < N_DIM);
    float* orow = out + ((long)b * N_DIM + n) * F_DIM;

#pragma unroll
    for (int j = 0; j < 2; ++j) {     // feature half: f = 4j .. 4j+3
        f32x4 rv[8];                  // rows lane..lane+7, half j
#pragma unroll
        for (int k = 0; k < 8; ++k) {
            int c = 2 * (lane + k) + j;
            rv[k] = *reinterpret_cast<const f32x4*>(
                wbase + ((c ^ ((c >> 3) & 7)) << 4));
        }
        float basev[4], acc[4];
#pragma unroll
        for (int f = 0; f < 4; ++f) {
            basev[f] = rv[0][f] * W[(4 * j + f) * K_DIM];   // W[f,0] scalar
            acc[f]   = 0.f;
        }
#pragma unroll
        for (int k = 0; k < 8; ++k) {
#pragma unroll
            for (int f = 0; f < 4; ++f) {
                float d = __builtin_fmaf(-W[(4 * j + f) * K_DIM + k + 1],
                                         rv[k][f], basev[f]);
                acc[f] += fabsf(d);   // v_add_f32 with abs() src modifier
            }
        }
        if (valid) {
            f32x4 o = { acc[0] + bb, acc[1] + bb, acc[2] + bb, acc[3] + bb };
            *reinterpret_cast<f32x4*>(orow + 4 * j) = o;
        }
    }
}

extern "C" void kernel_launch(void* const* d_in, const int* in_sizes, int n_in,
                              void* d_out, int out_size, void* d_ws, size_t ws_size,
                              hipStream_t stream) {
    const float* x    = (const float*)d_in[0];
    const float* W    = (const float*)d_in[1];
    const float* bias = (const float*)d_in[2];
    float* out        = (float*)d_out;

    dim3 grid(S_DIM / 256, BATCH);    // 64 x 32 = 2048 blocks, 256 thr each
    peak2peak_kernel<<<grid, 256, 0, stream>>>(x, W, bias, out);
}